// Round 4
// baseline (278.639 us; speedup 1.0000x reference)
//
#include <hip/hip_runtime.h>

#define T 4096
#define DM 1024
#define DK 64
#define H 16

typedef short s8 __attribute__((ext_vector_type(8)));   // 8 bf16 (4 VGPRs) MFMA frag
typedef float f4 __attribute__((ext_vector_type(4)));   // MFMA accumulator
typedef unsigned short us4 __attribute__((ext_vector_type(4)));
typedef unsigned u32x4 __attribute__((ext_vector_type(4)));
typedef __bf16 bf2 __attribute__((ext_vector_type(2)));

#define MFMA16(a,b,c) __builtin_amdgcn_mfma_f32_16x16x32_bf16((a),(b),(c),0,0,0)

__device__ __forceinline__ unsigned short f2bf(float x){
  __bf16 b = (__bf16)x;                      // hardware RNE cvt
  return __builtin_bit_cast(unsigned short, b);
}
__device__ __forceinline__ unsigned pk2(float a, float b){
  bf2 v; v[0] = (__bf16)a; v[1] = (__bf16)b; // -> v_cvt_pk_bf16_f32
  return __builtin_bit_cast(unsigned, v);
}

// async global->LDS, 16B per lane
__device__ __forceinline__ void gload16(const void* g, void* lds){
  __builtin_amdgcn_global_load_lds((const __attribute__((address_space(1))) unsigned int*)g,
                                   (__attribute__((address_space(3))) unsigned int*)lds,
                                   16, 0, 0);
}

// group exchange for P->A-frag redistribution
__device__ __forceinline__ void xch(unsigned X, unsigned Y, unsigned &E, unsigned &O){
#if __has_builtin(__builtin_amdgcn_permlane32_swap) && __has_builtin(__builtin_amdgcn_permlane16_swap)
  auto a = __builtin_amdgcn_permlane32_swap(X, Y, false, false);
  auto b = __builtin_amdgcn_permlane16_swap(a[0], a[1], false, false);
  E = b[0]; O = b[1];
#else
  int l = threadIdx.x & 63;
  int idxE = ((((l >> 4) & 1) * 32 + (l & 15))) << 2;
  unsigned eX = __builtin_amdgcn_ds_bpermute(idxE, X);
  unsigned eY = __builtin_amdgcn_ds_bpermute(idxE, Y);
  E = (l < 32) ? eX : eY;
  unsigned oX = __builtin_amdgcn_ds_bpermute(idxE + 64, X);
  unsigned oY = __builtin_amdgcn_ds_bpermute(idxE + 64, Y);
  O = (l < 32) ? oX : oY;
#endif
}

// ---- f32 -> bf16 convert (vectorized) ------------------------------------
__global__ void cvt_bf16(const float* __restrict__ in, unsigned short* __restrict__ out, int n4){
  int i = blockIdx.x * blockDim.x + threadIdx.x;
  if (i >= n4) return;
  float4 v = reinterpret_cast<const float4*>(in)[i];
  us4 o;
  o[0] = f2bf(v.x); o[1] = f2bf(v.y); o[2] = f2bf(v.z); o[3] = f2bf(v.w);
  reinterpret_cast<us4*>(out)[i] = o;
}

// ---- effective weights: Weff[o][m] = sum_k Wh[o][k]*Wbig[k][m] -----------
__global__ void prep_eff(const float* __restrict__ Wh, const float* __restrict__ Wbig,
                         const float* __restrict__ bbig, const float* __restrict__ bh,
                         unsigned short* __restrict__ Weff, float* __restrict__ beff,
                         float scale){
  int idx = blockIdx.x * 256 + threadIdx.x;
  int o = idx >> 10, m = idx & 1023;
  const float* wr = Wh + o * 64;
  float acc = 0.f;
  #pragma unroll 8
  for (int k = 0; k < 64; ++k) acc += wr[k] * Wbig[(size_t)k * DM + m];
  Weff[(size_t)o * DM + m] = f2bf(acc * scale);
  if (m == 0){
    float b = bh[o];
    for (int k = 0; k < 64; ++k) b += wr[k] * bbig[k];
    beff[o] = b * scale;
  }
}

// swizzled LDS read: slot s holds global chunk s^(row&7) (source pre-swizzled)
__device__ __forceinline__ s8 lds_frag(const short* base, int row, int cchunk){
  return *reinterpret_cast<const s8*>(base + (row * 8 + (cchunk ^ (row & 7))) * 8);
}

// ---- GEMM 128x128 tile, BK=64, 4 waves (2x2), dbuf prefetch --------------
// MODE 0: out bf16 at [(o>>6)][t][o&63]; MODE 1: out bf16 at [o][t];
// MODE 2: out f32 at [t][o]
template<int MODE>
__global__ __launch_bounds__(256) void gemm128(const unsigned short* __restrict__ A,
                       const unsigned short* __restrict__ B,
                       const float* __restrict__ bias, void* __restrict__ outp){
  __shared__ __align__(16) short la[2][128 * 64];
  __shared__ __align__(16) short lb[2][128 * 64];
  const int tid = threadIdx.x;
  const int wv = tid >> 6, l = tid & 63;
  const int lr = l & 15, lh = l >> 4;
  const int wr = wv >> 1, wc = wv & 1;
  const int tm = blockIdx.x >> 3, tn = blockIdx.x & 7;
  const int t0 = tm * 128, o0 = tn * 128;

  f4 acc[4][4];
  #pragma unroll
  for (int i = 0; i < 4; ++i)
    #pragma unroll
    for (int j = 0; j < 4; ++j) acc[i][j] = (f4){0.f, 0.f, 0.f, 0.f};

  auto stage = [&](int k0, int buf){
    #pragma unroll
    for (int c0 = 0; c0 < 1024; c0 += 256){
      int c = c0 + tid;
      int row = c >> 3, cs = (c & 7) ^ (row & 7);
      gload16(A + (size_t)(t0 + row) * DM + k0 + cs * 8, (void*)&la[buf][c * 8]);
      gload16(B + (size_t)(o0 + row) * DM + k0 + cs * 8, (void*)&lb[buf][c * 8]);
    }
  };

  stage(0, 0);
  __syncthreads();
  for (int kk = 0; kk < 16; ++kk){
    int cur = kk & 1;
    if (kk < 15) stage((kk + 1) * 64, cur ^ 1);
    s8 af[4][2], bf[4][2];
    #pragma unroll
    for (int mf = 0; mf < 4; ++mf){
      af[mf][0] = lds_frag(&la[cur][0], wr * 64 + mf * 16 + lr, lh);
      af[mf][1] = lds_frag(&la[cur][0], wr * 64 + mf * 16 + lr, 4 + lh);
    }
    #pragma unroll
    for (int nf = 0; nf < 4; ++nf){
      bf[nf][0] = lds_frag(&lb[cur][0], wc * 64 + nf * 16 + lr, lh);
      bf[nf][1] = lds_frag(&lb[cur][0], wc * 64 + nf * 16 + lr, 4 + lh);
    }
    __builtin_amdgcn_s_setprio(1);
    #pragma unroll
    for (int mf = 0; mf < 4; ++mf)
      #pragma unroll
      for (int nf = 0; nf < 4; ++nf){
        acc[mf][nf] = MFMA16(af[mf][0], bf[nf][0], acc[mf][nf]);
        acc[mf][nf] = MFMA16(af[mf][1], bf[nf][1], acc[mf][nf]);
      }
    __builtin_amdgcn_s_setprio(0);
    __syncthreads();
  }

  #pragma unroll
  for (int nf = 0; nf < 4; ++nf){
    int o = o0 + wc * 64 + nf * 16 + lr;
    float bs = bias[o];
    #pragma unroll
    for (int mf = 0; mf < 4; ++mf)
      #pragma unroll
      for (int r = 0; r < 4; ++r){
        int t = t0 + wr * 64 + mf * 16 + lh * 4 + r;
        float v = acc[mf][nf][r] + bs;
        if (MODE == 0)      ((unsigned short*)outp)[((size_t)(o >> 6) * T + t) * DK + (o & 63)] = f2bf(v);
        else if (MODE == 1) ((unsigned short*)outp)[(size_t)o * T + t] = f2bf(v);
        else                ((float*)outp)[(size_t)t * DM + o] = v;
      }
  }
}

// ---- flash attention v4: dbuf K/V with prefetch-before-compute -----------
__global__ __launch_bounds__(256) void attn_fwd(const unsigned short* __restrict__ qh,
                         const unsigned short* __restrict__ kh,
                         const unsigned short* __restrict__ vt,
                         unsigned short* __restrict__ cat){
  __shared__ __align__(16) short lk[2][64 * 64];
  __shared__ __align__(16) short lv[2][64 * 64];
  const int tid = threadIdx.x;
  const int wv = tid >> 6, l = tid & 63;
  const int lr = l & 15, lh = l >> 4;
  const int h = blockIdx.x >> 5, qblk = blockIdx.x & 31;
  const int Q0 = qblk * 128 + wv * 32;

  // Q as B-fragments (scale 0.125*log2e folded into Weff_q)
  s8 qf[2][2];
  #pragma unroll
  for (int qb = 0; qb < 2; ++qb)
    #pragma unroll
    for (int hf = 0; hf < 2; ++hf)
      qf[qb][hf] = *reinterpret_cast<const s8*>(
          qh + ((size_t)h * T + Q0 + qb * 16 + lr) * DK + hf * 32 + lh * 8);

  float mr[2] = {-1e30f, -1e30f}, ls[2] = {0.f, 0.f};
  f4 oa[2][4];
  #pragma unroll
  for (int qb = 0; qb < 2; ++qb)
    #pragma unroll
    for (int jb = 0; jb < 4; ++jb) oa[qb][jb] = (f4){0.f, 0.f, 0.f, 0.f};

  auto stage = [&](int it, int buf){
    int s0 = it * 64;
    #pragma unroll
    for (int c0 = 0; c0 < 512; c0 += 256){
      int c = c0 + tid;
      int row = c >> 3, cs = (c & 7) ^ (row & 7);
      gload16(kh + ((size_t)h * T + s0 + row) * DK + cs * 8, (void*)&lk[buf][c * 8]);
      gload16(vt + ((size_t)(h * DK + row)) * T + s0 + cs * 8, (void*)&lv[buf][c * 8]);
    }
  };

  stage(0, 0);
  __syncthreads();
  for (int it = 0; it < T / 64; ++it){
    int cur = it & 1;
    if (it < T / 64 - 1) stage(it + 1, cur ^ 1);

    s8 kf[4][2], vf[4][2];
    #pragma unroll
    for (int mt = 0; mt < 4; ++mt){
      kf[mt][0] = lds_frag(&lk[cur][0], mt * 16 + lr, lh);
      kf[mt][1] = lds_frag(&lk[cur][0], mt * 16 + lr, 4 + lh);
      vf[mt][0] = lds_frag(&lv[cur][0], mt * 16 + lr, lh);
      vf[mt][1] = lds_frag(&lv[cur][0], mt * 16 + lr, 4 + lh);
    }

    #pragma unroll
    for (int qb = 0; qb < 2; ++qb){
      // S^T tiles: lane(q=lr) holds S[q][kv = mt*16 + lh*4 + r]
      f4 sc[4];
      __builtin_amdgcn_s_setprio(1);
      #pragma unroll
      for (int mt = 0; mt < 4; ++mt){
        f4 z = (f4){0.f, 0.f, 0.f, 0.f};
        z = MFMA16(kf[mt][0], qf[qb][0], z);
        z = MFMA16(kf[mt][1], qf[qb][1], z);
        sc[mt] = z;
      }
      __builtin_amdgcn_s_setprio(0);
      // tile max + cross-half reduce
      float ma = fmaxf(fmaxf(sc[0][0], sc[0][1]), fmaxf(sc[0][2], sc[0][3]));
      float mb = fmaxf(fmaxf(sc[1][0], sc[1][1]), fmaxf(sc[1][2], sc[1][3]));
      float mc = fmaxf(fmaxf(sc[2][0], sc[2][1]), fmaxf(sc[2][2], sc[2][3]));
      float md = fmaxf(fmaxf(sc[3][0], sc[3][1]), fmaxf(sc[3][2], sc[3][3]));
      float mx = fmaxf(fmaxf(ma, mb), fmaxf(mc, md));
      mx = fmaxf(mx, __shfl_xor(mx, 16));
      mx = fmaxf(mx, __shfl_xor(mx, 32));
      // defer-max: only rescale when max grows materially (log2 domain)
      if (__any(mx > mr[qb] + 11.0f)){
        float mn = fmaxf(mr[qb], mx);
        float sf = __builtin_amdgcn_exp2f(mr[qb] - mn);
        mr[qb] = mn;
        ls[qb] *= sf;
        #pragma unroll
        for (int r = 0; r < 4; ++r){
          float sfr = __shfl(sf, lh * 4 + r);
          #pragma unroll
          for (int jb = 0; jb < 4; ++jb) oa[qb][jb][r] *= sfr;
        }
      }
      // P = exp2(S - m), row sum
      float p[4][4];
      float rs0 = 0.f, rs1 = 0.f;
      #pragma unroll
      for (int mt = 0; mt < 4; ++mt){
        p[mt][0] = __builtin_amdgcn_exp2f(sc[mt][0] - mr[qb]);
        p[mt][1] = __builtin_amdgcn_exp2f(sc[mt][1] - mr[qb]);
        p[mt][2] = __builtin_amdgcn_exp2f(sc[mt][2] - mr[qb]);
        p[mt][3] = __builtin_amdgcn_exp2f(sc[mt][3] - mr[qb]);
        rs0 += p[mt][0] + p[mt][1];
        rs1 += p[mt][2] + p[mt][3];
      }
      float rs = rs0 + rs1;
      rs += __shfl_xor(rs, 16);
      rs += __shfl_xor(rs, 32);
      ls[qb] += rs;
      // pack to bf16 pairs and permlane-exchange into A-frags
      unsigned w00 = pk2(p[0][0], p[0][1]), w01 = pk2(p[0][2], p[0][3]);
      unsigned w10 = pk2(p[1][0], p[1][1]), w11 = pk2(p[1][2], p[1][3]);
      unsigned w20 = pk2(p[2][0], p[2][1]), w21 = pk2(p[2][2], p[2][3]);
      unsigned w30 = pk2(p[3][0], p[3][1]), w31 = pk2(p[3][2], p[3][3]);
      unsigned e0, o0x, e1, o1x, e2, o2x, e3, o3x;
      xch(w00, w10, e0, o0x);
      xch(w01, w11, e1, o1x);
      xch(w20, w30, e2, o2x);
      xch(w21, w31, e3, o3x);
      u32x4 pa0u = {e0, e1, o0x, o1x};
      u32x4 pa1u = {e2, e3, o2x, o3x};
      s8 pa0 = __builtin_bit_cast(s8, pa0u);
      s8 pa1 = __builtin_bit_cast(s8, pa1u);
      // O += P·V
      __builtin_amdgcn_s_setprio(1);
      #pragma unroll
      for (int jb = 0; jb < 4; ++jb){
        oa[qb][jb] = MFMA16(pa0, vf[jb][0], oa[qb][jb]);
        oa[qb][jb] = MFMA16(pa1, vf[jb][1], oa[qb][jb]);
      }
      __builtin_amdgcn_s_setprio(0);
    }
    __syncthreads();
  }

  #pragma unroll
  for (int qb = 0; qb < 2; ++qb)
    #pragma unroll
    for (int r = 0; r < 4; ++r){
      float lsr = __shfl(ls[qb], lh * 4 + r);
      float inv = 1.f / lsr;
      int t = Q0 + qb * 16 + lh * 4 + r;
      #pragma unroll
      for (int jb = 0; jb < 4; ++jb)
        cat[(size_t)t * DM + h * DK + jb * 16 + lr] = f2bf(oa[qb][jb][r] * inv);
    }
}

// ---------------------------------------------------------------------------
extern "C" void kernel_launch(void* const* d_in, const int* in_sizes, int n_in,
                              void* d_out, int out_size, void* d_ws, size_t ws_size,
                              hipStream_t stream){
  const float* X   = (const float*)d_in[0];
  const float* Wq  = (const float*)d_in[1];
  const float* bq  = (const float*)d_in[2];
  const float* Wk  = (const float*)d_in[3];
  const float* bk  = (const float*)d_in[4];
  const float* Wv  = (const float*)d_in[5];
  const float* bv  = (const float*)d_in[6];
  const float* Whq = (const float*)d_in[7];
  const float* bhq = (const float*)d_in[8];
  const float* Whk = (const float*)d_in[9];
  const float* bhk = (const float*)d_in[10];
  const float* Whv = (const float*)d_in[11];
  const float* bhv = (const float*)d_in[12];
  const float* Wo  = (const float*)d_in[13];
  const float* bo  = (const float*)d_in[14];

  char* w = (char*)d_ws;
  size_t off = 0;
  auto alloc = [&](size_t bytes) -> char* {
    char* p = w + off;
    off = (off + bytes + 255) & ~(size_t)255;
    return p;
  };
  unsigned short* Xbf = (unsigned short*)alloc((size_t)T * DM * 2);
  unsigned short* Weq = (unsigned short*)alloc((size_t)DM * DM * 2);
  unsigned short* Wek = (unsigned short*)alloc((size_t)DM * DM * 2);
  unsigned short* Wev = (unsigned short*)alloc((size_t)DM * DM * 2);
  unsigned short* Wob = (unsigned short*)alloc((size_t)DM * DM * 2);
  float* beq = (float*)alloc(DM * 4);
  float* bek = (float*)alloc(DM * 4);
  float* bev = (float*)alloc(DM * 4);
  unsigned short* qhb = (unsigned short*)alloc((size_t)H * T * DK * 2);
  unsigned short* khb = (unsigned short*)alloc((size_t)H * T * DK * 2);
  unsigned short* vtb = (unsigned short*)alloc((size_t)H * T * DK * 2);
  unsigned short* cat = (unsigned short*)alloc((size_t)T * DM * 2);

  cvt_bf16<<<(T * DM / 4 + 255) / 256, 256, 0, stream>>>(X, Xbf, T * DM / 4);
  cvt_bf16<<<(DM * DM / 4 + 255) / 256, 256, 0, stream>>>(Wo, Wob, DM * DM / 4);

  // fold 1/sqrt(dk) * log2(e) into Q path (softmax runs in exp2 domain)
  prep_eff<<<DM * DM / 256, 256, 0, stream>>>(Whq, Wq, bq, bhq, Weq, beq, 0.18033688011112042f);
  prep_eff<<<DM * DM / 256, 256, 0, stream>>>(Whk, Wk, bk, bhk, Wek, bek, 1.0f);
  prep_eff<<<DM * DM / 256, 256, 0, stream>>>(Whv, Wv, bv, bhv, Wev, bev, 1.0f);

  gemm128<0><<<(T / 128) * (DM / 128), 256, 0, stream>>>(Xbf, Weq, beq, qhb);
  gemm128<0><<<(T / 128) * (DM / 128), 256, 0, stream>>>(Xbf, Wek, bek, khb);
  gemm128<1><<<(T / 128) * (DM / 128), 256, 0, stream>>>(Xbf, Wev, bev, vtb);

  attn_fwd<<<(T / 128) * H, 256, 0, stream>>>(qhb, khb, vtb, cat);

  gemm128<2><<<(T / 128) * (DM / 128), 256, 0, stream>>>(cat, Wob, bo, d_out);
}

// Round 5
// 277.138 us; speedup vs baseline: 1.0054x; 1.0054x over previous
//
#include <hip/hip_runtime.h>

#define T 4096
#define DM 1024
#define DK 64
#define H 16

typedef short s8 __attribute__((ext_vector_type(8)));   // 8 bf16 (4 VGPRs) MFMA frag
typedef float f4 __attribute__((ext_vector_type(4)));   // MFMA accumulator
typedef unsigned short us4 __attribute__((ext_vector_type(4)));
typedef unsigned u32x4 __attribute__((ext_vector_type(4)));
typedef __bf16 bf2 __attribute__((ext_vector_type(2)));

#define MFMA16(a,b,c) __builtin_amdgcn_mfma_f32_16x16x32_bf16((a),(b),(c),0,0,0)

__device__ __forceinline__ unsigned short f2bf(float x){
  __bf16 b = (__bf16)x;
  return __builtin_bit_cast(unsigned short, b);
}
__device__ __forceinline__ unsigned pk2(float a, float b){
  bf2 v; v[0] = (__bf16)a; v[1] = (__bf16)b; // -> v_cvt_pk_bf16_f32
  return __builtin_bit_cast(unsigned, v);
}

// async global->LDS, 16B per lane
__device__ __forceinline__ void gload16(const void* g, void* lds){
  __builtin_amdgcn_global_load_lds((const __attribute__((address_space(1))) unsigned int*)g,
                                   (__attribute__((address_space(3))) unsigned int*)lds,
                                   16, 0, 0);
}

// group exchange for P->A-frag redistribution
__device__ __forceinline__ void xch(unsigned X, unsigned Y, unsigned &E, unsigned &O){
#if __has_builtin(__builtin_amdgcn_permlane32_swap) && __has_builtin(__builtin_amdgcn_permlane16_swap)
  auto a = __builtin_amdgcn_permlane32_swap(X, Y, false, false);
  auto b = __builtin_amdgcn_permlane16_swap(a[0], a[1], false, false);
  E = b[0]; O = b[1];
#else
  int l = threadIdx.x & 63;
  int idxE = ((((l >> 4) & 1) * 32 + (l & 15))) << 2;
  unsigned eX = __builtin_amdgcn_ds_bpermute(idxE, X);
  unsigned eY = __builtin_amdgcn_ds_bpermute(idxE, Y);
  E = (l < 32) ? eX : eY;
  unsigned oX = __builtin_amdgcn_ds_bpermute(idxE + 64, X);
  unsigned oY = __builtin_amdgcn_ds_bpermute(idxE + 64, Y);
  O = (l < 32) ? oX : oY;
#endif
}

// ---- f32 -> bf16 convert (vectorized) ------------------------------------
__global__ void cvt_bf16(const float* __restrict__ in, unsigned short* __restrict__ out, int n4){
  int i = blockIdx.x * blockDim.x + threadIdx.x;
  if (i >= n4) return;
  float4 v = reinterpret_cast<const float4*>(in)[i];
  us4 o;
  o[0] = f2bf(v.x); o[1] = f2bf(v.y); o[2] = f2bf(v.z); o[3] = f2bf(v.w);
  reinterpret_cast<us4*>(out)[i] = o;
}

// ---- effective weights: Weff[o][m] = sum_k Wh[o][k]*Wbig[k][m] -----------
__global__ void prep_eff(const float* __restrict__ Wh, const float* __restrict__ Wbig,
                         const float* __restrict__ bbig, const float* __restrict__ bh,
                         unsigned short* __restrict__ Weff, float* __restrict__ beff,
                         float scale){
  int idx = blockIdx.x * 256 + threadIdx.x;
  int o = idx >> 10, m = idx & 1023;
  const float* wr = Wh + o * 64;
  float acc = 0.f;
  #pragma unroll 8
  for (int k = 0; k < 64; ++k) acc += wr[k] * Wbig[(size_t)k * DM + m];
  Weff[(size_t)o * DM + m] = f2bf(acc * scale);
  if (m == 0){
    float b = bh[o];
    for (int k = 0; k < 64; ++k) b += wr[k] * bbig[k];
    beff[o] = b * scale;
  }
}

// swizzled LDS read: slot s holds global chunk s^(row&7) (source pre-swizzled)
__device__ __forceinline__ s8 lds_frag(const short* base, int row, int cchunk){
  return *reinterpret_cast<const s8*>(base + (row * 8 + (cchunk ^ (row & 7))) * 8);
}

// ---- GEMM 128x64 tile, BK=64, 4 waves (2x2), dbuf prefetch ---------------
// MODE 3: fused QKV epilogue (o<1024 -> qhb [h][t][j]; <2048 -> khb; else vtb [j][t])
// MODE 2: out f32 at [t][o]
template<int MODE, int NT>
__global__ __launch_bounds__(256) void gemm_rt(const unsigned short* __restrict__ A,
                       const unsigned short* __restrict__ B,
                       const float* __restrict__ bias,
                       unsigned short* __restrict__ q_out,
                       unsigned short* __restrict__ k_out,
                       unsigned short* __restrict__ v_out,
                       float* __restrict__ f_out){
  __shared__ __align__(16) short la[2][128 * 64];
  __shared__ __align__(16) short lb[2][64 * 64];
  const int tid = threadIdx.x;
  const int wv = tid >> 6, l = tid & 63;
  const int lr = l & 15, lh = l >> 4;
  const int wr = wv >> 1, wc = wv & 1;
  const int tm = blockIdx.x / NT, tn = blockIdx.x % NT;
  const int t0 = tm * 128, o0 = tn * 64;

  f4 acc[4][2];
  #pragma unroll
  for (int i = 0; i < 4; ++i)
    #pragma unroll
    for (int j = 0; j < 2; ++j) acc[i][j] = (f4){0.f, 0.f, 0.f, 0.f};

  auto stage = [&](int k0, int buf){
    #pragma unroll
    for (int c0 = 0; c0 < 1024; c0 += 256){
      int c = c0 + tid;
      int row = c >> 3, cs = (c & 7) ^ (row & 7);
      gload16(A + (size_t)(t0 + row) * DM + k0 + cs * 8, (void*)&la[buf][c * 8]);
    }
    #pragma unroll
    for (int c0 = 0; c0 < 512; c0 += 256){
      int c = c0 + tid;
      int row = c >> 3, cs = (c & 7) ^ (row & 7);
      gload16(B + (size_t)(o0 + row) * DM + k0 + cs * 8, (void*)&lb[buf][c * 8]);
    }
  };

  stage(0, 0);
  __syncthreads();
  for (int kk = 0; kk < 16; ++kk){
    int cur = kk & 1;
    if (kk < 15) stage((kk + 1) * 64, cur ^ 1);
    s8 af[4][2], bfr[2][2];
    #pragma unroll
    for (int mf = 0; mf < 4; ++mf){
      af[mf][0] = lds_frag(&la[cur][0], wr * 64 + mf * 16 + lr, lh);
      af[mf][1] = lds_frag(&la[cur][0], wr * 64 + mf * 16 + lr, 4 + lh);
    }
    #pragma unroll
    for (int nf = 0; nf < 2; ++nf){
      bfr[nf][0] = lds_frag(&lb[cur][0], wc * 32 + nf * 16 + lr, lh);
      bfr[nf][1] = lds_frag(&lb[cur][0], wc * 32 + nf * 16 + lr, 4 + lh);
    }
    __builtin_amdgcn_s_setprio(1);
    #pragma unroll
    for (int mf = 0; mf < 4; ++mf)
      #pragma unroll
      for (int nf = 0; nf < 2; ++nf){
        acc[mf][nf] = MFMA16(af[mf][0], bfr[nf][0], acc[mf][nf]);
        acc[mf][nf] = MFMA16(af[mf][1], bfr[nf][1], acc[mf][nf]);
      }
    __builtin_amdgcn_s_setprio(0);
    __syncthreads();
  }

  #pragma unroll
  for (int nf = 0; nf < 2; ++nf){
    int o = o0 + wc * 32 + nf * 16 + lr;
    float bs = bias[o];
    int sel = o >> 10, oc = o & 1023;     // wave-uniform sel
    #pragma unroll
    for (int mf = 0; mf < 4; ++mf)
      #pragma unroll
      for (int r = 0; r < 4; ++r){
        int t = t0 + wr * 64 + mf * 16 + lh * 4 + r;
        float v = acc[mf][nf][r] + bs;
        if (MODE == 2){
          f_out[(size_t)t * DM + o] = v;
        } else {
          if (sel == 0)      q_out[((size_t)(oc >> 6) * T + t) * DK + (oc & 63)] = f2bf(v);
          else if (sel == 1) k_out[((size_t)(oc >> 6) * T + t) * DK + (oc & 63)] = f2bf(v);
          else               v_out[(size_t)oc * T + t] = f2bf(v);
        }
      }
  }
}

// ---- flash attention, KV-split x2: writes raw f32 partials + (m,l) -------
__global__ __launch_bounds__(256) void attn_fwd(const unsigned short* __restrict__ qh,
                         const unsigned short* __restrict__ kh,
                         const unsigned short* __restrict__ vt,
                         float* __restrict__ Op, float2* __restrict__ ml){
  __shared__ __align__(16) short lk[2][64 * 64];
  __shared__ __align__(16) short lv[2][64 * 64];
  const int tid = threadIdx.x;
  const int wv = tid >> 6, l = tid & 63;
  const int lr = l & 15, lh = l >> 4;
  const int half = blockIdx.x & 1;
  const int qblk = (blockIdx.x >> 1) & 31;
  const int h = blockIdx.x >> 6;
  const int Q0 = qblk * 128 + wv * 32;
  const int IT0 = half * 32;

  s8 qf[2][2];
  #pragma unroll
  for (int qb = 0; qb < 2; ++qb)
    #pragma unroll
    for (int hf = 0; hf < 2; ++hf)
      qf[qb][hf] = *reinterpret_cast<const s8*>(
          qh + ((size_t)h * T + Q0 + qb * 16 + lr) * DK + hf * 32 + lh * 8);

  float mr[2] = {-1e30f, -1e30f}, ls[2] = {0.f, 0.f};
  f4 oa[2][4];
  #pragma unroll
  for (int qb = 0; qb < 2; ++qb)
    #pragma unroll
    for (int jb = 0; jb < 4; ++jb) oa[qb][jb] = (f4){0.f, 0.f, 0.f, 0.f};

  auto stage = [&](int it, int buf){
    int s0 = (IT0 + it) * 64;
    #pragma unroll
    for (int c0 = 0; c0 < 512; c0 += 256){
      int c = c0 + tid;
      int row = c >> 3, cs = (c & 7) ^ (row & 7);
      gload16(kh + ((size_t)h * T + s0 + row) * DK + cs * 8, (void*)&lk[buf][c * 8]);
      gload16(vt + ((size_t)(h * DK + row)) * T + s0 + cs * 8, (void*)&lv[buf][c * 8]);
    }
  };

  stage(0, 0);
  __syncthreads();
  for (int it = 0; it < 32; ++it){
    int cur = it & 1;
    if (it < 31) stage(it + 1, cur ^ 1);

    s8 kf[4][2], vf[4][2];
    #pragma unroll
    for (int mt = 0; mt < 4; ++mt){
      kf[mt][0] = lds_frag(&lk[cur][0], mt * 16 + lr, lh);
      kf[mt][1] = lds_frag(&lk[cur][0], mt * 16 + lr, 4 + lh);
      vf[mt][0] = lds_frag(&lv[cur][0], mt * 16 + lr, lh);
      vf[mt][1] = lds_frag(&lv[cur][0], mt * 16 + lr, 4 + lh);
    }

    #pragma unroll
    for (int qb = 0; qb < 2; ++qb){
      f4 sc[4];
      __builtin_amdgcn_s_setprio(1);
      #pragma unroll
      for (int mt = 0; mt < 4; ++mt){
        f4 z = (f4){0.f, 0.f, 0.f, 0.f};
        z = MFMA16(kf[mt][0], qf[qb][0], z);
        z = MFMA16(kf[mt][1], qf[qb][1], z);
        sc[mt] = z;
      }
      __builtin_amdgcn_s_setprio(0);
      float ma = fmaxf(fmaxf(sc[0][0], sc[0][1]), fmaxf(sc[0][2], sc[0][3]));
      float mb = fmaxf(fmaxf(sc[1][0], sc[1][1]), fmaxf(sc[1][2], sc[1][3]));
      float mc = fmaxf(fmaxf(sc[2][0], sc[2][1]), fmaxf(sc[2][2], sc[2][3]));
      float md = fmaxf(fmaxf(sc[3][0], sc[3][1]), fmaxf(sc[3][2], sc[3][3]));
      float mx = fmaxf(fmaxf(ma, mb), fmaxf(mc, md));
      mx = fmaxf(mx, __shfl_xor(mx, 16));
      mx = fmaxf(mx, __shfl_xor(mx, 32));
      if (__any(mx > mr[qb] + 11.0f)){
        float mn = fmaxf(mr[qb], mx);
        float sf = __builtin_amdgcn_exp2f(mr[qb] - mn);
        mr[qb] = mn;
        ls[qb] *= sf;
        #pragma unroll
        for (int r = 0; r < 4; ++r){
          float sfr = __shfl(sf, lh * 4 + r);
          #pragma unroll
          for (int jb = 0; jb < 4; ++jb) oa[qb][jb][r] *= sfr;
        }
      }
      float p[4][4];
      float rs0 = 0.f, rs1 = 0.f;
      #pragma unroll
      for (int mt = 0; mt < 4; ++mt){
        p[mt][0] = __builtin_amdgcn_exp2f(sc[mt][0] - mr[qb]);
        p[mt][1] = __builtin_amdgcn_exp2f(sc[mt][1] - mr[qb]);
        p[mt][2] = __builtin_amdgcn_exp2f(sc[mt][2] - mr[qb]);
        p[mt][3] = __builtin_amdgcn_exp2f(sc[mt][3] - mr[qb]);
        rs0 += p[mt][0] + p[mt][1];
        rs1 += p[mt][2] + p[mt][3];
      }
      float rs = rs0 + rs1;
      rs += __shfl_xor(rs, 16);
      rs += __shfl_xor(rs, 32);
      ls[qb] += rs;
      unsigned w00 = pk2(p[0][0], p[0][1]), w01 = pk2(p[0][2], p[0][3]);
      unsigned w10 = pk2(p[1][0], p[1][1]), w11 = pk2(p[1][2], p[1][3]);
      unsigned w20 = pk2(p[2][0], p[2][1]), w21 = pk2(p[2][2], p[2][3]);
      unsigned w30 = pk2(p[3][0], p[3][1]), w31 = pk2(p[3][2], p[3][3]);
      unsigned e0, o0x, e1, o1x, e2, o2x, e3, o3x;
      xch(w00, w10, e0, o0x);
      xch(w01, w11, e1, o1x);
      xch(w20, w30, e2, o2x);
      xch(w21, w31, e3, o3x);
      u32x4 pa0u = {e0, e1, o0x, o1x};
      u32x4 pa1u = {e2, e3, o2x, o3x};
      s8 pa0 = __builtin_bit_cast(s8, pa0u);
      s8 pa1 = __builtin_bit_cast(s8, pa1u);
      __builtin_amdgcn_s_setprio(1);
      #pragma unroll
      for (int jb = 0; jb < 4; ++jb){
        oa[qb][jb] = MFMA16(pa0, vf[jb][0], oa[qb][jb]);
        oa[qb][jb] = MFMA16(pa1, vf[jb][1], oa[qb][jb]);
      }
      __builtin_amdgcn_s_setprio(0);
    }
    __syncthreads();
  }

  // write raw partials + (m, l)
  const size_t base = ((size_t)(half * H + h) * T);
  if (lh == 0){
    #pragma unroll
    for (int qb = 0; qb < 2; ++qb)
      ml[base + Q0 + qb * 16 + lr] = make_float2(mr[qb], ls[qb]);
  }
  #pragma unroll
  for (int qb = 0; qb < 2; ++qb)
    #pragma unroll
    for (int r = 0; r < 4; ++r){
      size_t row = base + Q0 + qb * 16 + lh * 4 + r;
      #pragma unroll
      for (int jb = 0; jb < 4; ++jb)
        Op[(row << 6) + jb * 16 + lr] = oa[qb][jb][r];
    }
}

// ---- combine two KV halves -> cat (bf16 [t][h*64+j]) ---------------------
__global__ __launch_bounds__(256) void attn_combine(const float* __restrict__ Op,
                              const float2* __restrict__ ml,
                              unsigned short* __restrict__ cat){
  int idx = blockIdx.x * 256 + threadIdx.x;       // over H*T*64
  int j = idx & 63;
  int t = (idx >> 6) & (T - 1);
  int h = idx >> 18;
  float2 m0 = ml[(size_t)h * T + t];
  float2 m1 = ml[(size_t)(H + h) * T + t];
  float m = fmaxf(m0.x, m1.x);
  float w0 = __builtin_amdgcn_exp2f(m0.x - m);
  float w1 = __builtin_amdgcn_exp2f(m1.x - m);
  float o0 = Op[(((size_t)h * T + t) << 6) + j];
  float o1 = Op[(((size_t)(H + h) * T + t) << 6) + j];
  float v = (o0 * w0 + o1 * w1) / (m0.y * w0 + m1.y * w1);
  cat[(size_t)t * DM + h * DK + j] = f2bf(v);
}

// ---------------------------------------------------------------------------
extern "C" void kernel_launch(void* const* d_in, const int* in_sizes, int n_in,
                              void* d_out, int out_size, void* d_ws, size_t ws_size,
                              hipStream_t stream){
  const float* X   = (const float*)d_in[0];
  const float* Wq  = (const float*)d_in[1];
  const float* bq  = (const float*)d_in[2];
  const float* Wk  = (const float*)d_in[3];
  const float* bk  = (const float*)d_in[4];
  const float* Wv  = (const float*)d_in[5];
  const float* bv  = (const float*)d_in[6];
  const float* Whq = (const float*)d_in[7];
  const float* bhq = (const float*)d_in[8];
  const float* Whk = (const float*)d_in[9];
  const float* bhk = (const float*)d_in[10];
  const float* Whv = (const float*)d_in[11];
  const float* bhv = (const float*)d_in[12];
  const float* Wo  = (const float*)d_in[13];
  const float* bo  = (const float*)d_in[14];

  char* w = (char*)d_ws;
  size_t off = 0;
  auto alloc = [&](size_t bytes) -> char* {
    char* p = w + off;
    off = (off + bytes + 255) & ~(size_t)255;
    return p;
  };
  unsigned short* Xbf  = (unsigned short*)alloc((size_t)T * DM * 2);   // reused as cat
  unsigned short* Wef3 = (unsigned short*)alloc((size_t)3 * DM * DM * 2);
  unsigned short* Wob  = (unsigned short*)alloc((size_t)DM * DM * 2);
  float* bef3 = (float*)alloc(3 * DM * 4);
  unsigned short* qhb = (unsigned short*)alloc((size_t)H * T * DK * 2);
  unsigned short* khb = (unsigned short*)alloc((size_t)H * T * DK * 2);
  unsigned short* vtb = (unsigned short*)alloc((size_t)H * T * DK * 2);
  float*  Oparts = (float*)alloc((size_t)2 * H * T * DK * 4);
  float2* mlbuf  = (float2*)alloc((size_t)2 * H * T * 8);
  unsigned short* cat = Xbf;   // alias: Xbf dead after QKV GEMM

  cvt_bf16<<<(T * DM / 4 + 255) / 256, 256, 0, stream>>>(X, Xbf, T * DM / 4);
  cvt_bf16<<<(DM * DM / 4 + 255) / 256, 256, 0, stream>>>(Wo, Wob, DM * DM / 4);

  // fold 1/sqrt(dk) * log2(e) into Q path (softmax runs in exp2 domain)
  prep_eff<<<DM * DM / 256, 256, 0, stream>>>(Whq, Wq, bq, bhq, Wef3, bef3, 0.18033688011112042f);
  prep_eff<<<DM * DM / 256, 256, 0, stream>>>(Whk, Wk, bk, bhk, Wef3 + (size_t)DM * DM, bef3 + DM, 1.0f);
  prep_eff<<<DM * DM / 256, 256, 0, stream>>>(Whv, Wv, bv, bhv, Wef3 + (size_t)2 * DM * DM, bef3 + 2 * DM, 1.0f);

  // fused QKV projection: 4096 x 3072 x 1024
  gemm_rt<3, 48><<<(T / 128) * 48, 256, 0, stream>>>(Xbf, Wef3, bef3, qhb, khb, vtb, nullptr);

  // attention with KV split x2
  attn_fwd<<<(T / 128) * H * 2, 256, 0, stream>>>(qhb, khb, vtb, Oparts, mlbuf);
  attn_combine<<<(H * T * DK) / 256, 256, 0, stream>>>(Oparts, mlbuf, cat);

  // final projection (f32 out)
  gemm_rt<2, 16><<<(T / 128) * 16, 256, 0, stream>>>(cat, Wob, bo, nullptr, nullptr, nullptr, (float*)d_out);
}

// Round 6
// 248.232 us; speedup vs baseline: 1.1225x; 1.1164x over previous
//
#include <hip/hip_runtime.h>

#define T 4096
#define DM 1024
#define DK 64
#define H 16

typedef short s8 __attribute__((ext_vector_type(8)));   // 8 bf16 (4 VGPRs) MFMA frag
typedef float f4 __attribute__((ext_vector_type(4)));   // MFMA accumulator
typedef unsigned short us4 __attribute__((ext_vector_type(4)));
typedef unsigned u32x4 __attribute__((ext_vector_type(4)));
typedef __bf16 bf2 __attribute__((ext_vector_type(2)));

#define MFMA16(a,b,c) __builtin_amdgcn_mfma_f32_16x16x32_bf16((a),(b),(c),0,0,0)

__device__ __forceinline__ unsigned short f2bf(float x){
  __bf16 b = (__bf16)x;
  return __builtin_bit_cast(unsigned short, b);
}
__device__ __forceinline__ unsigned pk2(float a, float b){
  bf2 v; v[0] = (__bf16)a; v[1] = (__bf16)b; // -> v_cvt_pk_bf16_f32
  return __builtin_bit_cast(unsigned, v);
}
__device__ __forceinline__ float fmax3(float a, float b, float c){
  return fmaxf(fmaxf(a, b), c);              // -> v_max3_f32
}

// async global->LDS, 16B per lane
__device__ __forceinline__ void gload16(const void* g, void* lds){
  __builtin_amdgcn_global_load_lds((const __attribute__((address_space(1))) unsigned int*)g,
                                   (__attribute__((address_space(3))) unsigned int*)lds,
                                   16, 0, 0);
}

// group exchange for P->A-frag redistribution
__device__ __forceinline__ void xch(unsigned X, unsigned Y, unsigned &E, unsigned &O){
#if __has_builtin(__builtin_amdgcn_permlane32_swap) && __has_builtin(__builtin_amdgcn_permlane16_swap)
  auto a = __builtin_amdgcn_permlane32_swap(X, Y, false, false);
  auto b = __builtin_amdgcn_permlane16_swap(a[0], a[1], false, false);
  E = b[0]; O = b[1];
#else
  int l = threadIdx.x & 63;
  int idxE = ((((l >> 4) & 1) * 32 + (l & 15))) << 2;
  unsigned eX = __builtin_amdgcn_ds_bpermute(idxE, X);
  unsigned eY = __builtin_amdgcn_ds_bpermute(idxE, Y);
  E = (l < 32) ? eX : eY;
  unsigned oX = __builtin_amdgcn_ds_bpermute(idxE + 64, X);
  unsigned oY = __builtin_amdgcn_ds_bpermute(idxE + 64, Y);
  O = (l < 32) ? oX : oY;
#endif
}

// ---- f32 -> bf16 convert (vectorized) ------------------------------------
__global__ void cvt_bf16(const float* __restrict__ in, unsigned short* __restrict__ out, int n4){
  int i = blockIdx.x * blockDim.x + threadIdx.x;
  if (i >= n4) return;
  float4 v = reinterpret_cast<const float4*>(in)[i];
  us4 o;
  o[0] = f2bf(v.x); o[1] = f2bf(v.y); o[2] = f2bf(v.z); o[3] = f2bf(v.w);
  reinterpret_cast<us4*>(out)[i] = o;
}

// ---- effective weights: Weff[o][m] = sum_k Wh[o][k]*Wbig[k][m] -----------
__global__ void prep_eff(const float* __restrict__ Wh, const float* __restrict__ Wbig,
                         const float* __restrict__ bbig, const float* __restrict__ bh,
                         unsigned short* __restrict__ Weff, float* __restrict__ beff,
                         float scale){
  int idx = blockIdx.x * 256 + threadIdx.x;
  int o = idx >> 10, m = idx & 1023;
  const float* wr = Wh + o * 64;
  float acc = 0.f;
  #pragma unroll 8
  for (int k = 0; k < 64; ++k) acc += wr[k] * Wbig[(size_t)k * DM + m];
  Weff[(size_t)o * DM + m] = f2bf(acc * scale);
  if (m == 0){
    float b = bh[o];
    for (int k = 0; k < 64; ++k) b += wr[k] * bbig[k];
    beff[o] = b * scale;
  }
}

// ---- GEMM: 128xBN tile, BK=64, 4 waves (2x2), dbuf, strength-reduced -----
// MODE 3: fused QKV epilogue; MODE 2: f32 out [t][o]
template<int MODE, int BN, int NT>
__global__ __launch_bounds__(256) void gemmX(const unsigned short* __restrict__ A,
                       const unsigned short* __restrict__ B,
                       const float* __restrict__ bias,
                       unsigned short* __restrict__ q_out,
                       unsigned short* __restrict__ k_out,
                       unsigned short* __restrict__ v_out,
                       float* __restrict__ f_out){
  __shared__ __align__(16) short la[2][128 * 64];
  __shared__ __align__(16) short lb[2][BN * 64];
  const int tid = threadIdx.x;
  const int wv = tid >> 6, l = tid & 63;
  const int lr = l & 15, lh = l >> 4;
  const int wr = wv >> 1, wc = wv & 1;
  const int tm = blockIdx.x / NT, tn = blockIdx.x % NT;
  const int t0 = tm * 128, o0 = tn * BN;
  constexpr int NF = BN / 32;                 // n-frags per wave
  constexpr int BCH = BN * 64 / (8 * 256);    // B staging chunks per thread
  constexpr int LBB = BN * 128;               // lb bytes per buf

  f4 acc[4][NF];
  #pragma unroll
  for (int i = 0; i < 4; ++i)
    #pragma unroll
    for (int j = 0; j < NF; ++j) acc[i][j] = (f4){0.f, 0.f, 0.f, 0.f};

  // staging lane constants (strength-reduced pointers)
  const int srow = tid >> 3;
  const int scs  = (tid & 7) ^ (srow & 7);
  const unsigned short* ap = A + (size_t)(t0 + srow) * DM + scs * 8;
  const unsigned short* bp = B + (size_t)(o0 + srow) * DM + scs * 8;
  char* ad = (char*)&la[0][0] + tid * 16;
  char* bd = (char*)&lb[0][0] + tid * 16;

  auto stage = [&](int BUF){
    #pragma unroll
    for (int i = 0; i < 4; ++i)
      gload16(ap + (size_t)i * 32 * DM, ad + BUF * 16384 + i * 4096);
    #pragma unroll
    for (int i = 0; i < BCH; ++i)
      gload16(bp + (size_t)i * 32 * DM, bd + BUF * LBB + i * 4096);
    ap += 64; bp += 64;
  };

  // fragment lane bases (bytes); per-read offsets are compile-time immediates
  const int asw0 = (lh ^ (lr & 7)) * 16, asw1 = ((lh ^ 4) ^ (lr & 7)) * 16;
  const char* aB0 = (const char*)&la[0][0] + (wr * 64 + lr) * 128 + asw0;
  const char* aB1 = (const char*)&la[0][0] + (wr * 64 + lr) * 128 + asw1;
  const char* bB0 = (const char*)&lb[0][0] + (wc * (BN / 2) + lr) * 128 + asw0;
  const char* bB1 = (const char*)&lb[0][0] + (wc * (BN / 2) + lr) * 128 + asw1;

  auto step = [&](int BUF, bool dostage){
    if (dostage) stage(BUF ^ 1);
    s8 af[4][2], bfr[NF][2];
    #pragma unroll
    for (int mf = 0; mf < 4; ++mf){
      af[mf][0] = *(const s8*)(aB0 + BUF * 16384 + mf * 2048);
      af[mf][1] = *(const s8*)(aB1 + BUF * 16384 + mf * 2048);
    }
    #pragma unroll
    for (int nf = 0; nf < NF; ++nf){
      bfr[nf][0] = *(const s8*)(bB0 + BUF * LBB + nf * 2048);
      bfr[nf][1] = *(const s8*)(bB1 + BUF * LBB + nf * 2048);
    }
    __builtin_amdgcn_s_setprio(1);
    #pragma unroll
    for (int mf = 0; mf < 4; ++mf)
      #pragma unroll
      for (int nf = 0; nf < NF; ++nf){
        acc[mf][nf] = MFMA16(af[mf][0], bfr[nf][0], acc[mf][nf]);
        acc[mf][nf] = MFMA16(af[mf][1], bfr[nf][1], acc[mf][nf]);
      }
    __builtin_amdgcn_s_setprio(0);
    __syncthreads();
  };

  stage(0);
  __syncthreads();
  #pragma unroll 1
  for (int t2 = 0; t2 < 8; ++t2){
    step(0, true);
    step(1, t2 < 7);
  }

  #pragma unroll
  for (int nf = 0; nf < NF; ++nf){
    int o = o0 + wc * (BN / 2) + nf * 16 + lr;
    float bs = bias[o];
    int sel = o >> 10, oc = o & 1023;     // wave-uniform sel
    #pragma unroll
    for (int mf = 0; mf < 4; ++mf)
      #pragma unroll
      for (int r = 0; r < 4; ++r){
        int t = t0 + wr * 64 + mf * 16 + lh * 4 + r;
        float v = acc[mf][nf][r] + bs;
        if (MODE == 2){
          f_out[(size_t)t * DM + o] = v;
        } else {
          if (sel == 0)      q_out[((size_t)(oc >> 6) * T + t) * DK + (oc & 63)] = f2bf(v);
          else if (sel == 1) k_out[((size_t)(oc >> 6) * T + t) * DK + (oc & 63)] = f2bf(v);
          else               v_out[(size_t)oc * T + t] = f2bf(v);
        }
      }
  }
}

// ---- flash attention v6: instruction-diet, dbuf, direct bf16 out ---------
__global__ __launch_bounds__(256) void attn_fwd(const unsigned short* __restrict__ qh,
                         const unsigned short* __restrict__ kh,
                         const unsigned short* __restrict__ vt,
                         unsigned short* __restrict__ cat){
  __shared__ __align__(16) short lk[2][64 * 64];
  __shared__ __align__(16) short lv[2][64 * 64];
  const int tid = threadIdx.x;
  const int wv = tid >> 6, l = tid & 63;
  const int lr = l & 15, lh = l >> 4;
  const int h = blockIdx.x >> 5, qblk = blockIdx.x & 31;
  const int Q0 = qblk * 128 + wv * 32;

  s8 qf[2][2];
  #pragma unroll
  for (int qb = 0; qb < 2; ++qb)
    #pragma unroll
    for (int hf = 0; hf < 2; ++hf)
      qf[qb][hf] = *reinterpret_cast<const s8*>(
          qh + ((size_t)h * T + Q0 + qb * 16 + lr) * DK + hf * 32 + lh * 8);

  float mr[2] = {-1e30f, -1e30f}, ls[2] = {0.f, 0.f};
  f4 oa[2][4];
  #pragma unroll
  for (int qb = 0; qb < 2; ++qb)
    #pragma unroll
    for (int jb = 0; jb < 4; ++jb) oa[qb][jb] = (f4){0.f, 0.f, 0.f, 0.f};

  // staging lane constants (strength-reduced pointers)
  const int srow = tid >> 3;
  const int scs  = (tid & 7) ^ (srow & 7);
  const unsigned short* kp = kh + (size_t)h * T * DK + srow * DK + scs * 8;
  const unsigned short* vp = vt + (size_t)h * DK * T + srow * T + scs * 8;
  char* kd = (char*)&lk[0][0] + tid * 16;
  char* vd = (char*)&lv[0][0] + tid * 16;

  auto stage = [&](int BUF){
    gload16(kp,           kd + BUF * 8192);
    gload16(kp + 32 * DK, kd + BUF * 8192 + 4096);
    gload16(vp,           vd + BUF * 8192);
    gload16(vp + 32 * T,  vd + BUF * 8192 + 4096);
    kp += 64 * DK; vp += 64;
  };

  const int sw0 = (lh ^ (lr & 7)) * 16, sw1 = ((lh ^ 4) ^ (lr & 7)) * 16;
  const char* kB0 = (const char*)&lk[0][0] + lr * 128 + sw0;
  const char* kB1 = (const char*)&lk[0][0] + lr * 128 + sw1;
  const char* vB0 = (const char*)&lv[0][0] + lr * 128 + sw0;
  const char* vB1 = (const char*)&lv[0][0] + lr * 128 + sw1;

  auto step = [&](int BUF, bool dostage){
    if (dostage) stage(BUF ^ 1);
    s8 kf[4][2], vf[4][2];
    #pragma unroll
    for (int mt = 0; mt < 4; ++mt){
      kf[mt][0] = *(const s8*)(kB0 + BUF * 8192 + mt * 2048);
      kf[mt][1] = *(const s8*)(kB1 + BUF * 8192 + mt * 2048);
      vf[mt][0] = *(const s8*)(vB0 + BUF * 8192 + mt * 2048);
      vf[mt][1] = *(const s8*)(vB1 + BUF * 8192 + mt * 2048);
    }
    #pragma unroll
    for (int qb = 0; qb < 2; ++qb){
      f4 sc[4];
      __builtin_amdgcn_s_setprio(1);
      #pragma unroll
      for (int mt = 0; mt < 4; ++mt){
        f4 z = (f4){0.f, 0.f, 0.f, 0.f};
        z = MFMA16(kf[mt][0], qf[qb][0], z);
        z = MFMA16(kf[mt][1], qf[qb][1], z);
        sc[mt] = z;
      }
      __builtin_amdgcn_s_setprio(0);
      // tile max via max3 tree + cross-half reduce
      float m0 = fmax3(sc[0][0], sc[0][1], sc[0][2]);
      float m1 = fmax3(sc[0][3], sc[1][0], sc[1][1]);
      float m2 = fmax3(sc[1][2], sc[1][3], sc[2][0]);
      float m3 = fmax3(sc[2][1], sc[2][2], sc[2][3]);
      float m4 = fmax3(sc[3][0], sc[3][1], sc[3][2]);
      float mx = fmax3(fmax3(m0, m1, sc[3][3]), m2, fmax3(m3, m4, mr[qb]));
      mx = fmaxf(mx, __shfl_xor(mx, 16));
      mx = fmaxf(mx, __shfl_xor(mx, 32));
      // defer-max: only rescale when max grows materially (log2 domain)
      if (__any(mx > mr[qb] + 11.0f)){
        float sf = __builtin_amdgcn_exp2f(mr[qb] - mx);
        mr[qb] = mx;
        ls[qb] *= sf;
        #pragma unroll
        for (int r = 0; r < 4; ++r){
          float sfr = __shfl(sf, lh * 4 + r);
          #pragma unroll
          for (int jb = 0; jb < 4; ++jb) oa[qb][jb][r] *= sfr;
        }
      }
      float p[4][4];
      float rs0 = 0.f, rs1 = 0.f;
      #pragma unroll
      for (int mt = 0; mt < 4; ++mt){
        p[mt][0] = __builtin_amdgcn_exp2f(sc[mt][0] - mr[qb]);
        p[mt][1] = __builtin_amdgcn_exp2f(sc[mt][1] - mr[qb]);
        p[mt][2] = __builtin_amdgcn_exp2f(sc[mt][2] - mr[qb]);
        p[mt][3] = __builtin_amdgcn_exp2f(sc[mt][3] - mr[qb]);
        rs0 += p[mt][0] + p[mt][1];
        rs1 += p[mt][2] + p[mt][3];
      }
      float rs = rs0 + rs1;
      rs += __shfl_xor(rs, 16);
      rs += __shfl_xor(rs, 32);
      ls[qb] += rs;
      unsigned w00 = pk2(p[0][0], p[0][1]), w01 = pk2(p[0][2], p[0][3]);
      unsigned w10 = pk2(p[1][0], p[1][1]), w11 = pk2(p[1][2], p[1][3]);
      unsigned w20 = pk2(p[2][0], p[2][1]), w21 = pk2(p[2][2], p[2][3]);
      unsigned w30 = pk2(p[3][0], p[3][1]), w31 = pk2(p[3][2], p[3][3]);
      unsigned e0, o0x, e1, o1x, e2, o2x, e3, o3x;
      xch(w00, w10, e0, o0x);
      xch(w01, w11, e1, o1x);
      xch(w20, w30, e2, o2x);
      xch(w21, w31, e3, o3x);
      u32x4 pa0u = {e0, e1, o0x, o1x};
      u32x4 pa1u = {e2, e3, o2x, o3x};
      s8 pa0 = __builtin_bit_cast(s8, pa0u);
      s8 pa1 = __builtin_bit_cast(s8, pa1u);
      __builtin_amdgcn_s_setprio(1);
      #pragma unroll
      for (int jb = 0; jb < 4; ++jb){
        oa[qb][jb] = MFMA16(pa0, vf[jb][0], oa[qb][jb]);
        oa[qb][jb] = MFMA16(pa1, vf[jb][1], oa[qb][jb]);
      }
      __builtin_amdgcn_s_setprio(0);
    }
    __syncthreads();
  };

  stage(0);
  __syncthreads();
  #pragma unroll 1
  for (int t2 = 0; t2 < 32; ++t2){
    step(0, true);
    step(1, t2 < 31);
  }

  #pragma unroll
  for (int qb = 0; qb < 2; ++qb)
    #pragma unroll
    for (int r = 0; r < 4; ++r){
      float lsr = __shfl(ls[qb], lh * 4 + r);
      float inv = 1.f / lsr;
      int t = Q0 + qb * 16 + lh * 4 + r;
      #pragma unroll
      for (int jb = 0; jb < 4; ++jb)
        cat[(size_t)t * DM + h * DK + jb * 16 + lr] = f2bf(oa[qb][jb][r] * inv);
    }
}

// ---------------------------------------------------------------------------
extern "C" void kernel_launch(void* const* d_in, const int* in_sizes, int n_in,
                              void* d_out, int out_size, void* d_ws, size_t ws_size,
                              hipStream_t stream){
  const float* X   = (const float*)d_in[0];
  const float* Wq  = (const float*)d_in[1];
  const float* bq  = (const float*)d_in[2];
  const float* Wk  = (const float*)d_in[3];
  const float* bk  = (const float*)d_in[4];
  const float* Wv  = (const float*)d_in[5];
  const float* bv  = (const float*)d_in[6];
  const float* Whq = (const float*)d_in[7];
  const float* bhq = (const float*)d_in[8];
  const float* Whk = (const float*)d_in[9];
  const float* bhk = (const float*)d_in[10];
  const float* Whv = (const float*)d_in[11];
  const float* bhv = (const float*)d_in[12];
  const float* Wo  = (const float*)d_in[13];
  const float* bo  = (const float*)d_in[14];

  char* w = (char*)d_ws;
  size_t off = 0;
  auto alloc = [&](size_t bytes) -> char* {
    char* p = w + off;
    off = (off + bytes + 255) & ~(size_t)255;
    return p;
  };
  unsigned short* Xbf  = (unsigned short*)alloc((size_t)T * DM * 2);   // reused as cat
  unsigned short* Wef3 = (unsigned short*)alloc((size_t)3 * DM * DM * 2);
  unsigned short* Wob  = (unsigned short*)alloc((size_t)DM * DM * 2);
  float* bef3 = (float*)alloc(3 * DM * 4);
  unsigned short* qhb = (unsigned short*)alloc((size_t)H * T * DK * 2);
  unsigned short* khb = (unsigned short*)alloc((size_t)H * T * DK * 2);
  unsigned short* vtb = (unsigned short*)alloc((size_t)H * T * DK * 2);
  unsigned short* cat = Xbf;   // alias: Xbf dead after QKV GEMM

  cvt_bf16<<<(T * DM / 4 + 255) / 256, 256, 0, stream>>>(X, Xbf, T * DM / 4);
  cvt_bf16<<<(DM * DM / 4 + 255) / 256, 256, 0, stream>>>(Wo, Wob, DM * DM / 4);

  // fold 1/sqrt(dk) * log2(e) into Q path (softmax runs in exp2 domain)
  prep_eff<<<DM * DM / 256, 256, 0, stream>>>(Whq, Wq, bq, bhq, Wef3, bef3, 0.18033688011112042f);
  prep_eff<<<DM * DM / 256, 256, 0, stream>>>(Whk, Wk, bk, bhk, Wef3 + (size_t)DM * DM, bef3 + DM, 1.0f);
  prep_eff<<<DM * DM / 256, 256, 0, stream>>>(Whv, Wv, bv, bhv, Wef3 + (size_t)2 * DM * DM, bef3 + 2 * DM, 1.0f);

  // fused QKV projection: 4096 x 3072 x 1024, 128x128 tiles
  gemmX<3, 128, 24><<<(T / 128) * 24, 256, 0, stream>>>(Xbf, Wef3, bef3, qhb, khb, vtb, nullptr);

  // attention (full KV per block)
  attn_fwd<<<(T / 128) * H, 256, 0, stream>>>(qhb, khb, vtb, cat);

  // final projection (f32 out), 128x64 tiles
  gemmX<2, 64, 16><<<(T / 128) * 16, 256, 0, stream>>>(cat, Wob, bo, nullptr, nullptr, nullptr, (float*)d_out);
}